// Round 6
// baseline (3421.384 us; speedup 1.0000x reference)
//
#include <hip/hip_runtime.h>
#include <cstdint>

// GptOssExpertsLinear: E=16, H=D=2880, T=2048.
// out[t,h] = sum_e rw[t,e] * ( act(x@Wg[e]+bg, x@Wu[e]+bu) @ Wd[e] + bd )
// R6: 6-wave blocks, tile 256x288, wave tile 128x96 (reads/MFMA 0.292 vs
// 0.417) to cut LDS-read + staging-VALU per FLOP by ~30%. Gate/up pairing
// via paired weight layout (48-col blocks) built by tcvt. Down: one expert
// per block -> pout[16] fp32 partials -> reduce.

#define ALPHA 1.702f
#define LIMIT 7.0f

static constexpr int E = 16;
static constexpr int H = 2880;
static constexpr int D = 2880;
static constexpr int T = 2048;
static constexpr int NKT = H / 64;   // 45 K-steps

typedef float        f32x4  __attribute__((ext_vector_type(4)));
typedef short        bf16x8 __attribute__((ext_vector_type(8)));

#define MFMA_BF16(a,b,c) __builtin_amdgcn_mfma_f32_16x16x32_bf16((a),(b),(c),0,0,0)
#define SBAR()        __builtin_amdgcn_s_barrier()
#define SCHED_FENCE() __builtin_amdgcn_sched_barrier(0)

__device__ __forceinline__ unsigned short f2bf(float f){
  unsigned u = __builtin_bit_cast(unsigned, f);
  u += 0x7fffu + ((u >> 16) & 1u);
  return (unsigned short)(u >> 16);
}
__device__ __forceinline__ unsigned pack2(float a, float b){
  return (unsigned)f2bf(a) | ((unsigned)f2bf(b) << 16);
}

__device__ __forceinline__ void gload_lds16(const void* g, void* l){
  __builtin_amdgcn_global_load_lds((const __attribute__((address_space(1))) unsigned*)g,
                                   (__attribute__((address_space(3))) unsigned*)l,
                                   16, 0, 0);
}

// x fp32 -> bf16, 8 elems/thread
__global__ void cvt_kernel(const float* __restrict__ in, unsigned short* __restrict__ ob, int n8){
  int i = blockIdx.x * 256 + threadIdx.x;
  if (i < n8){
    float4 a = ((const float4*)in)[2*i];
    float4 b = ((const float4*)in)[2*i+1];
    uint4 o;
    o.x = pack2(a.x, a.y); o.y = pack2(a.z, a.w);
    o.z = pack2(b.x, b.y); o.w = pack2(b.z, b.w);
    ((uint4*)ob)[i] = o;
  }
}

// W[2880][2880] fp32 -> bf16 transpose with row remap.
// mode 0: dst row = (c/48)*96 + c%48       (gate half of paired layout)
// mode 1: dst row = (c/48)*96 + c%48 + 48  (up half)
// mode 2: dst row = c                      (plain transpose, down weights)
__global__ __launch_bounds__(256) void tcvt_kernel(
    const float* __restrict__ src, unsigned short* __restrict__ dst,
    int mode, size_t dstExpStride)
{
  __shared__ unsigned short tl[64*72];
  const int t = threadIdx.x;
  const float* s = src + (size_t)blockIdx.z * H * D;
  unsigned short* o = dst + (size_t)blockIdx.z * dstExpStride;
  const int r0 = blockIdx.x * 64, c0 = blockIdx.y * 64;

  int rr = t >> 2;
  #pragma unroll
  for (int p = 0; p < 4; ++p){
    int cc = ((t & 3) + p*4) * 4;
    float4 v = *(const float4*)(s + (size_t)(r0 + rr)*D + c0 + cc);
    tl[(cc+0)*72 + rr] = f2bf(v.x);
    tl[(cc+1)*72 + rr] = f2bf(v.y);
    tl[(cc+2)*72 + rr] = f2bf(v.z);
    tl[(cc+3)*72 + rr] = f2bf(v.w);
  }
  __syncthreads();
  #pragma unroll
  for (int p = 0; p < 2; ++p){
    int task = p*256 + t;
    int cl = task >> 3, ch = task & 7;
    int c = c0 + cl;
    int rowp = (mode < 2) ? ((c/48)*96 + (c%48) + mode*48) : c;
    bf16x8 v = *(const bf16x8*)&tl[cl*72 + ch*8];
    *(bf16x8*)(o + (size_t)rowp*H + r0 + ch*8) = v;
  }
}

// sum the 16 per-expert partials -> out
__global__ void reduce_kernel(const float* __restrict__ p, float* __restrict__ out, int n4){
  int i = blockIdx.x * 256 + threadIdx.x;
  if (i < n4){
    f32x4 a = ((const f32x4*)p)[i];
    #pragma unroll
    for (int g = 1; g < E; ++g)
      a += ((const f32x4*)(p + (size_t)g * T * H))[i];
    ((f32x4*)out)[i] = a;
  }
}

// ---------------- gate+up fused GEMM + activation ----------------
// grid (8, 20, ec); 384 thr = 6 waves (2M x 3N); wave tile 128 x 96'
// (96' = 48 gate cols + 48 up cols for the same d's, paired layout).
__global__ __launch_bounds__(384, 2) void gateup_kernel(
    const unsigned short* __restrict__ xb,    // [T][H] bf16
    const unsigned short* __restrict__ wGU,   // [ec][5760'][H] paired bf16
    const float* __restrict__ bg,
    const float* __restrict__ bu,
    unsigned short* __restrict__ inter,       // [ec][T][D] bf16
    int e0)
{
  __shared__ short As[2][256*64];   // 64KB
  __shared__ short Bs[2][288*64];   // 72KB => 136KB total, 1 block/CU

  const int t = threadIdx.x, lane = t & 63, wv = t >> 6;
  const int wm = wv / 3, wn = wv % 3;

  int nbx = gridDim.x, nby = gridDim.y;
  int lin = blockIdx.x + nbx*(blockIdx.y + nby*blockIdx.z);
  int per = (nbx*nby*gridDim.z) >> 3;
  int id2 = (lin & 7)*per + (lin >> 3);
  int bx = id2 % nbx; int rem = id2 / nbx;
  int by = rem % nby; int ez = rem / nby;

  const int trow0 = bx * 256, ncol0p = by * 288;
  const int e = e0 + ez;
  const unsigned short* wg = wGU + (size_t)ez * 2 * D * H;

  f32x4 acc[8][6];
  #pragma unroll
  for (int i = 0; i < 8; ++i)
    #pragma unroll
    for (int j = 0; j < 6; ++j) acc[i][j] = (f32x4){0.f,0.f,0.f,0.f};

  auto stage = [&](int kt, int buf){
    // A: 2048 16B chunks; rounds 0-4 full, round 5 duplicated (wave-uniform)
    #pragma unroll
    for (int r = 0; r < 6; ++r){
      int task = (r < 5) ? (r*384 + t) : (1920 + (t & 127));
      int row = task >> 3, ch = task & 7, sch = ch ^ (row & 7);
      gload_lds16(xb + (size_t)(trow0 + row)*H + kt*64 + sch*8, &As[buf][task*8]);
    }
    // B: 2304 16B chunks, exactly 6/thread
    #pragma unroll
    for (int r = 0; r < 6; ++r){
      int task = r*384 + t;
      int row = task >> 3, ch = task & 7, sch = ch ^ (row & 7);
      gload_lds16(wg + (size_t)(ncol0p + row)*H + kt*64 + sch*8, &Bs[buf][task*8]);
    }
  };

  stage(0, 0);   // 12 vmem in flight

  for (int kt = 0; kt < NKT; ++kt){
    int cur = kt & 1, nxt = cur ^ 1;
    int ktn = (kt+1 < NKT) ? kt+1 : kt;
    stage(ktn, nxt);                      // 24 outstanding
    asm volatile("s_waitcnt vmcnt(12)" ::: "memory");   // stage(kt) landed
    SCHED_FENCE(); SBAR(); SCHED_FENCE();
    #pragma unroll
    for (int kk = 0; kk < 2; ++kk){
      bf16x8 af[8];
      #pragma unroll
      for (int mi = 0; mi < 8; ++mi){
        int row = wm*128 + mi*16 + (lane & 15);
        int pc  = (kk*4 + (lane>>4)) ^ (row & 7);
        af[mi] = *(const bf16x8*)&As[cur][row*64 + pc*8];
      }
      #pragma unroll
      for (int ni = 0; ni < 6; ++ni){
        int rowB = wn*96 + ni*16 + (lane & 15);
        int pc   = (kk*4 + (lane>>4)) ^ (rowB & 7);
        bf16x8 fb = *(const bf16x8*)&Bs[cur][rowB*64 + pc*8];
        #pragma unroll
        for (int mi = 0; mi < 8; ++mi)
          acc[mi][ni] = MFMA_BF16(af[mi], fb, acc[mi][ni]);
      }
    }
    SBAR();
  }
  asm volatile("s_waitcnt vmcnt(0)" ::: "memory");

  // epilogue: ni g (gate) pairs with ni g+3 (up), same d
  const float* bgp = bg + (size_t)e * D;
  const float* bup = bu + (size_t)e * D;
  unsigned short* ip = inter + (size_t)ez * T * D;
  #pragma unroll
  for (int g = 0; g < 3; ++g){
    int d = by*144 + wn*48 + g*16 + (lane & 15);
    float bgv = bgp[d], buv = bup[d];
    #pragma unroll
    for (int mi = 0; mi < 8; ++mi){
      #pragma unroll
      for (int r = 0; r < 4; ++r){
        int trw = trow0 + wm*128 + mi*16 + (lane >> 4)*4 + r;
        float gv = acc[mi][g][r] + bgv;
        float uv = acc[mi][g+3][r] + buv;
        gv = fminf(gv, LIMIT);
        uv = fminf(fmaxf(uv, -LIMIT), LIMIT);
        float glu = gv / (1.f + __expf(-ALPHA * gv));
        ip[(size_t)trw * D + d] = f2bf((uv + 1.f) * glu);
      }
    }
  }
}

// ---------------- down GEMM -> per-expert weighted partial ----------------
// grid (8, 10, ec); 384 thr = 6 waves; tile 256x288; wave tile 128x96.
__global__ __launch_bounds__(384, 2) void down_kernel(
    const unsigned short* __restrict__ inter, // [ec][T][D] bf16
    const unsigned short* __restrict__ wdT,   // [ec][H][D] bf16 (n-major)
    const float* __restrict__ bd,
    const float* __restrict__ rw,             // [T][E]
    float* __restrict__ pout,                 // [E][T][H] fp32 partials
    int e0)
{
  __shared__ short As[2][256*64];   // 64KB
  __shared__ short Bs[2][288*64];   // 72KB

  const int t = threadIdx.x, lane = t & 63, wv = t >> 6;
  const int wm = wv / 3, wn = wv % 3;

  int nbx = gridDim.x, nby = gridDim.y;
  int lin = blockIdx.x + nbx*(blockIdx.y + nby*blockIdx.z);
  int per = (nbx*nby*gridDim.z) >> 3;
  int id2 = (lin & 7)*per + (lin >> 3);
  int bx = id2 % nbx; int rem = id2 / nbx;
  int by = rem % nby; int ez = rem / nby;

  const int trow0 = bx * 256, ncol0 = by * 288;
  const int e = e0 + ez;
  const unsigned short* ap = inter + (size_t)ez * T * D;
  const unsigned short* wd = wdT + (size_t)ez * H * D;

  f32x4 acc[8][6];
  #pragma unroll
  for (int i = 0; i < 8; ++i)
    #pragma unroll
    for (int j = 0; j < 6; ++j) acc[i][j] = (f32x4){0.f,0.f,0.f,0.f};

  auto stage = [&](int kt, int buf){
    #pragma unroll
    for (int r = 0; r < 6; ++r){
      int task = (r < 5) ? (r*384 + t) : (1920 + (t & 127));
      int row = task >> 3, ch = task & 7, sch = ch ^ (row & 7);
      gload_lds16(ap + (size_t)(trow0 + row)*D + kt*64 + sch*8, &As[buf][task*8]);
    }
    #pragma unroll
    for (int r = 0; r < 6; ++r){
      int task = r*384 + t;
      int row = task >> 3, ch = task & 7, sch = ch ^ (row & 7);
      gload_lds16(wd + (size_t)(ncol0 + row)*D + kt*64 + sch*8, &Bs[buf][task*8]);
    }
  };

  stage(0, 0);

  for (int kt = 0; kt < NKT; ++kt){
    int cur = kt & 1, nxt = cur ^ 1;
    int ktn = (kt+1 < NKT) ? kt+1 : kt;
    stage(ktn, nxt);
    asm volatile("s_waitcnt vmcnt(12)" ::: "memory");
    SCHED_FENCE(); SBAR(); SCHED_FENCE();
    #pragma unroll
    for (int kk = 0; kk < 2; ++kk){
      bf16x8 af[8];
      #pragma unroll
      for (int mi = 0; mi < 8; ++mi){
        int row = wm*128 + mi*16 + (lane & 15);
        int pc  = (kk*4 + (lane>>4)) ^ (row & 7);
        af[mi] = *(const bf16x8*)&As[cur][row*64 + pc*8];
      }
      #pragma unroll
      for (int ni = 0; ni < 6; ++ni){
        int rowB = wn*96 + ni*16 + (lane & 15);
        int pc   = (kk*4 + (lane>>4)) ^ (rowB & 7);
        bf16x8 fb = *(const bf16x8*)&Bs[cur][rowB*64 + pc*8];
        #pragma unroll
        for (int mi = 0; mi < 8; ++mi)
          acc[mi][ni] = MFMA_BF16(af[mi], fb, acc[mi][ni]);
      }
    }
    SBAR();
  }
  asm volatile("s_waitcnt vmcnt(0)" ::: "memory");

  // epilogue: pout[e] = rw[t,e] * (acc + bd)
  const float* bdp = bd + (size_t)e * H;
  float* pp = pout + (size_t)e * T * H;
  float rvv[8][4];
  #pragma unroll
  for (int mi = 0; mi < 8; ++mi)
    #pragma unroll
    for (int r = 0; r < 4; ++r)
      rvv[mi][r] = rw[(trow0 + wm*128 + mi*16 + (lane>>4)*4 + r)*E + e];
  #pragma unroll
  for (int ni = 0; ni < 6; ++ni){
    int h = ncol0 + wn*96 + ni*16 + (lane & 15);
    float bdv = bdp[h];
    #pragma unroll
    for (int mi = 0; mi < 8; ++mi){
      #pragma unroll
      for (int r = 0; r < 4; ++r){
        int trw = trow0 + wm*128 + mi*16 + (lane >> 4)*4 + r;
        pp[(size_t)trw * H + h] = rvv[mi][r] * (acc[mi][ni][r] + bdv);
      }
    }
  }
}

extern "C" void kernel_launch(void* const* d_in, const int* in_sizes, int n_in,
                              void* d_out, int out_size, void* d_ws, size_t ws_size,
                              hipStream_t stream) {
  const float* hs  = (const float*)d_in[0];
  const float* rwt = (const float*)d_in[1];
  const float* Wg  = (const float*)d_in[2];
  const float* bg  = (const float*)d_in[3];
  const float* Wu  = (const float*)d_in[4];
  const float* bu  = (const float*)d_in[5];
  const float* Wd  = (const float*)d_in[6];
  const float* bd  = (const float*)d_in[7];
  float* out = (float*)d_out;

  const size_t xbytes = (size_t)T * H * 2;          // 11.8 MB
  const size_t poutB  = (size_t)E * T * H * 4;      // 377 MB
  const size_t interB = (size_t)T * D * 2;          // 11.8 MB / expert
  const size_t guB    = (size_t)2 * D * H * 2;      // 33.2 MB / expert (paired)
  const size_t perE   = interB + guB;               // ~45 MB / expert

  long long avail = (long long)ws_size - (long long)(xbytes + poutB);
  int EC = (int)(avail / (long long)perE);
  if (EC < 1) EC = 1;
  if (EC > E) EC = E;

  unsigned short* xb    = (unsigned short*)d_ws;
  float*          pout  = (float*)((char*)d_ws + xbytes);
  unsigned short* inter = (unsigned short*)((char*)d_ws + xbytes + poutB);
  unsigned short* wGU   = (unsigned short*)((char*)d_ws + xbytes + poutB + (size_t)EC*interB);
  // wdT aliases wGU (stream-serialized: gateup consumes wGU before down tcvt)

  cvt_kernel<<<(T*H/8 + 255)/256, 256, 0, stream>>>(hs, xb, T*H/8);

  for (int e0 = 0; e0 < E; e0 += EC){
    int ec = (E - e0 < EC) ? (E - e0) : EC;
    tcvt_kernel<<<dim3(45,45,ec), 256, 0, stream>>>(Wg + (size_t)e0*H*D, wGU, 0, (size_t)2*D*H);
    tcvt_kernel<<<dim3(45,45,ec), 256, 0, stream>>>(Wu + (size_t)e0*H*D, wGU, 1, (size_t)2*D*H);
    gateup_kernel<<<dim3(8, 20, ec), 384, 0, stream>>>(xb, wGU, bg, bu, inter, e0);
    tcvt_kernel<<<dim3(45,45,ec), 256, 0, stream>>>(Wd + (size_t)e0*D*H, wGU, 2, (size_t)D*H);
    down_kernel<<<dim3(8, 10, ec), 384, 0, stream>>>(inter, wGU, bd, rwt, pout, e0);
  }
  reduce_kernel<<<(T*H/4 + 255)/256, 256, 0, stream>>>(pout, out, T*H/4);
}